// Round 2
// baseline (1126.044 us; speedup 1.0000x reference)
//
#include <hip/hip_runtime.h>
#include <stdint.h>

#define BB 64
#define TT 512
#define EE 256
#define NTAG 4

typedef _Float16 f16;
typedef _Float16 half8 __attribute__((ext_vector_type(8)));
typedef _Float16 f16x4 __attribute__((ext_vector_type(4)));
typedef float floatx4 __attribute__((ext_vector_type(4)));

__device__ __forceinline__ int dot4i8(uint32_t a, uint32_t b, int c) {
#if __has_builtin(__builtin_amdgcn_sdot4)
  return __builtin_amdgcn_sdot4((int)a, (int)b, c, false);
#else
  int r;
  asm("v_dot4_i32_i8 %0, %1, %2, %3" : "=v"(r) : "v"(a), "v"(b), "v"(c));
  return r;
#endif
}

__device__ __forceinline__ float sigm(float x) {
  x = fminf(fmaxf(x, -30.f), 30.f);
  return 1.f / (1.f + __expf(-x));
}
__device__ __forceinline__ float tanh_f(float x) {
  x = fminf(fmaxf(x, -15.f), 15.f);
  float e = __expf(-2.f * x);
  return (1.f - e) / (1.f + e);
}

// ---------------- pack: w_ih -> f16 Bmat rows (gate-interleaved output cols);
//                   w_hh -> i8 k4-major + row scales
__global__ void pack_kernel(const float* __restrict__ wihf, const float* __restrict__ wihb,
                            const float* __restrict__ whhf, const float* __restrict__ whhb,
                            f16* __restrict__ bmat, uint32_t* __restrict__ whhp,
                            float* __restrict__ swhh) {
  int wv = (blockIdx.x * 256 + threadIdx.x) >> 6;  // global wave 0..2047
  int lane = threadIdx.x & 63;
  if (wv >= 2048) return;
  int dir = wv >> 10;
  int outr = wv & 1023;  // output col index: dim = outr>>2, gate = outr&3
  // Bmat (w_ih as f16), source row = gate*256 + dim
  int srcg = (outr & 3) * 256 + (outr >> 2);
  const float* wih = dir ? wihb : wihf;
  const float* src = wih + (size_t)srcg * EE + lane * 4;
  f16* bp = bmat + (size_t)wv * EE + lane * 4;
  floatx4 v = *(const floatx4*)src;
  bp[0] = (f16)v[0]; bp[1] = (f16)v[1]; bp[2] = (f16)v[2]; bp[3] = (f16)v[3];
  // w_hh quantize (row index = outr, original layout)
  int g = outr;
  const float* whh = dir ? whhb : whhf;
  floatx4 w = *(const floatx4*)(whh + (size_t)g * EE + lane * 4);
  float am = fmaxf(fmaxf(fabsf(w[0]), fabsf(w[1])), fmaxf(fabsf(w[2]), fabsf(w[3])));
#pragma unroll
  for (int d = 1; d < 64; d <<= 1) am = fmaxf(am, __shfl_xor(am, d));
  float s = am * (1.f / 127.f);
  float inv = am > 0.f ? 127.f / am : 0.f;
  int q0 = (int)rintf(w[0] * inv);
  int q1 = (int)rintf(w[1] * inv);
  int q2 = (int)rintf(w[2] * inv);
  int q3 = (int)rintf(w[3] * inv);
  uint32_t p = (uint32_t)(q0 & 255) | ((uint32_t)(q1 & 255) << 8) |
               ((uint32_t)(q2 & 255) << 16) | ((uint32_t)(q3 & 255) << 24);
  // layout [dir][k4=lane][g]
  whhp[dir * 65536 + lane * 1024 + g] = p;
  if (lane == 0) swhh[dir * 1024 + g] = s;
}

// ---------------- GEMM: xg = embeds @ w_ih^T  (f16 MFMA, fused embedding gather)
__global__ __launch_bounds__(256) void gemm_kernel(
    const int* __restrict__ sentence, const float* __restrict__ embedding,
    const f16* __restrict__ bmat, f16* __restrict__ xgF, f16* __restrict__ xgB,
    int t0f, int t0b, int L, int Lsh) {
  __shared__ __attribute__((aligned(16))) f16 As[128][72];
  __shared__ __attribute__((aligned(16))) f16 Bs[128][72];
  int rt = blockIdx.x;
  int nt = blockIdx.y;  // 0..7
  int tid = threadIdx.x;
  int lane = tid & 63;
  int wv = tid >> 6;
  int BL = BB * L;
  int rbase = rt * 128;
  int half = (rbase >= BL) ? 1 : 0;
  int rloc0 = rbase - half * BL;
  int t0 = half ? t0b : t0f;

  floatx4 acc[4][4];
#pragma unroll
  for (int i = 0; i < 4; ++i)
#pragma unroll
    for (int j = 0; j < 4; ++j) acc[i][j] = (floatx4){0.f, 0.f, 0.f, 0.f};

  int ar = tid >> 1;    // 0..127 staging row
  int part = tid & 1;   // k-half of 64
  int rl = rloc0 + ar;
  int b_ = rl >> Lsh;
  int dt = rl & (L - 1);
  int t_ = t0 + dt;
  int sidx = sentence[b_ * TT + t_];
  const float* arow = embedding + (size_t)sidx * EE + part * 32;
  const f16* brow = bmat + ((size_t)(half * 1024 + nt * 128 + ar)) * EE + part * 32;
  int wm = (wv >> 1) * 64, wn = (wv & 1) * 64;

  for (int kk = 0; kk < 4; ++kk) {
    int k0 = kk * 64;
#pragma unroll
    for (int i = 0; i < 4; ++i) {
      floatx4 a0 = *(const floatx4*)(arow + k0 + i * 8);
      floatx4 a1 = *(const floatx4*)(arow + k0 + i * 8 + 4);
      union { f16 h[8]; uint4 u; } cv;
      cv.h[0] = (f16)a0[0]; cv.h[1] = (f16)a0[1]; cv.h[2] = (f16)a0[2]; cv.h[3] = (f16)a0[3];
      cv.h[4] = (f16)a1[0]; cv.h[5] = (f16)a1[1]; cv.h[6] = (f16)a1[2]; cv.h[7] = (f16)a1[3];
      *(uint4*)(&As[ar][part * 32 + i * 8]) = cv.u;
    }
#pragma unroll
    for (int i = 0; i < 4; ++i) {
      uint4 bv = *(const uint4*)(brow + k0 + i * 8);
      *(uint4*)(&Bs[ar][part * 32 + i * 8]) = bv;
    }
    __syncthreads();
#pragma unroll
    for (int kf = 0; kf < 2; ++kf) {
      int ko = kf * 32 + (lane >> 4) * 8;
      half8 af[4], bf[4];
#pragma unroll
      for (int mi = 0; mi < 4; ++mi)
        af[mi] = *(const half8*)(&As[wm + mi * 16 + (lane & 15)][ko]);
#pragma unroll
      for (int ni = 0; ni < 4; ++ni)
        bf[ni] = *(const half8*)(&Bs[wn + ni * 16 + (lane & 15)][ko]);
#pragma unroll
      for (int mi = 0; mi < 4; ++mi)
#pragma unroll
        for (int ni = 0; ni < 4; ++ni)
          acc[mi][ni] = __builtin_amdgcn_mfma_f32_16x16x32_f16(af[mi], bf[ni], acc[mi][ni], 0, 0, 0);
    }
    __syncthreads();
  }
  f16* out = half ? xgB : xgF;
#pragma unroll
  for (int mi = 0; mi < 4; ++mi) {
#pragma unroll
    for (int ni = 0; ni < 4; ++ni) {
      int rowl = wm + mi * 16 + (lane >> 4) * 4;
      int coll = nt * 128 + wn + ni * 16 + (lane & 15);
#pragma unroll
      for (int r = 0; r < 4; ++r) {
        out[(size_t)(rloc0 + rowl + r) * 1024 + coll] = (f16)acc[mi][ni][r];
      }
    }
  }
}

// ---------------- recurrence: 128 WGs (b,dir), 256 threads, 1 h-dim/thread,
//                   4 gate rows (i8) register-resident, single barrier/step
__global__ __launch_bounds__(256, 1) void rec_kernel(
    const int* __restrict__ length, const f16* __restrict__ xgF, const f16* __restrict__ xgB,
    const uint32_t* __restrict__ whhp, const float* __restrict__ swhh,
    const float* __restrict__ b_f, const float* __restrict__ b_b,
    f16* __restrict__ hsF, f16* __restrict__ hsB,
    float* __restrict__ hstate, float* __restrict__ cstate,
    int t0f, int t0b, int L, int first) {
  __shared__ __attribute__((aligned(16))) uint32_t hq4[2][64];
  int wid = blockIdx.x;
  int b = wid >> 1, dir = wid & 1;
  int j = threadIdx.x;  // h dim 0..255
  int len = length[b];

  const uint32_t* wp = whhp + dir * 65536;
  uint32_t wr0[64], wr1[64], wr2[64], wr3[64];
#pragma unroll
  for (int q = 0; q < 64; ++q) {
    wr0[q] = wp[q * 1024 + j];
    wr1[q] = wp[q * 1024 + 256 + j];
    wr2[q] = wp[q * 1024 + 512 + j];
    wr3[q] = wp[q * 1024 + 768 + j];
  }
  const float* sb = swhh + dir * 1024;
  float sw0 = sb[j] * (1.f / 127.f), sw1 = sb[256 + j] * (1.f / 127.f);
  float sw2 = sb[512 + j] * (1.f / 127.f), sw3 = sb[768 + j] * (1.f / 127.f);
  const float* bias = dir ? b_b : b_f;
  float bi0 = bias[j], bi1 = bias[256 + j], bi2 = bias[512 + j], bi3 = bias[768 + j];

  float h = 0.f, c = 0.f;
  if (!first) {
    h = hstate[(dir * BB + b) * 256 + j];
    c = cstate[(dir * BB + b) * 256 + j];
  }
  const f16* xg = dir ? xgB : xgF;
  f16* hs = dir ? hsB : hsF;

  int qi = (int)rintf(h * 127.f);
  qi = max(-127, min(127, qi));
  ((uint8_t*)&hq4[0][0])[j] = (uint8_t)qi;
  __syncthreads();

  int tlo = dir ? t0b : t0f;
  int thi = min(tlo + L, len);
  int nsteps = thi - tlo;
  int p = 0;
  for (int ii = 0; ii < nsteps; ++ii) {
    int t = dir ? (thi - 1 - ii) : (tlo + ii);
    f16x4 xv = *(const f16x4*)(xg + (((size_t)(b * L + (t - tlo))) << 10) + j * 4);
    int A00 = 0, A01 = 0, A10 = 0, A11 = 0, A20 = 0, A21 = 0, A30 = 0, A31 = 0;
#pragma unroll
    for (int k = 0; k < 16; ++k) {
      uint4 v = *((const uint4*)&hq4[p][0] + k);
      A00 = dot4i8(wr0[4 * k + 0], v.x, A00); A01 = dot4i8(wr0[4 * k + 1], v.y, A01);
      A00 = dot4i8(wr0[4 * k + 2], v.z, A00); A01 = dot4i8(wr0[4 * k + 3], v.w, A01);
      A10 = dot4i8(wr1[4 * k + 0], v.x, A10); A11 = dot4i8(wr1[4 * k + 1], v.y, A11);
      A10 = dot4i8(wr1[4 * k + 2], v.z, A10); A11 = dot4i8(wr1[4 * k + 3], v.w, A11);
      A20 = dot4i8(wr2[4 * k + 0], v.x, A20); A21 = dot4i8(wr2[4 * k + 1], v.y, A21);
      A20 = dot4i8(wr2[4 * k + 2], v.z, A20); A21 = dot4i8(wr2[4 * k + 3], v.w, A21);
      A30 = dot4i8(wr3[4 * k + 0], v.x, A30); A31 = dot4i8(wr3[4 * k + 1], v.y, A31);
      A30 = dot4i8(wr3[4 * k + 2], v.z, A30); A31 = dot4i8(wr3[4 * k + 3], v.w, A31);
    }
    float pi = (float)xv[0] + bi0 + sw0 * (float)(A00 + A01);
    float pf = (float)xv[1] + bi1 + sw1 * (float)(A10 + A11);
    float pg = (float)xv[2] + bi2 + sw2 * (float)(A20 + A21);
    float po = (float)xv[3] + bi3 + sw3 * (float)(A30 + A31);
    float iv = sigm(pi), fv = sigm(pf), gv = tanh_f(pg), ov = sigm(po);
    c = fv * c + iv * gv;
    h = ov * tanh_f(c);
    hs[(((size_t)(b * TT + t)) << 8) + j] = (f16)h;  // fire-and-forget
    int q = (int)rintf(h * 127.f);
    q = max(-127, min(127, q));
    ((uint8_t*)&hq4[p ^ 1][0])[j] = (uint8_t)q;
    __syncthreads();
    p ^= 1;
  }
  hstate[(dir * BB + b) * 256 + j] = h;
  cstate[(dir * BB + b) * 256 + j] = c;
}

// ---------------- feats: [hf|hb] @ w_out^T + b_out, one wave per row
__global__ __launch_bounds__(256) void feats_kernel(
    const f16* __restrict__ hsF, const f16* __restrict__ hsB,
    const float* __restrict__ w_out, const float* __restrict__ b_out,
    float* __restrict__ feats) {
  int gw = (blockIdx.x * 256 + threadIdx.x) >> 6;
  int lane = threadIdx.x & 63;
  int nw = (gridDim.x * 256) >> 6;
  float w0[8], w1[8], w2[8], w3[8];
#pragma unroll
  for (int u = 0; u < 8; ++u) {
    w0[u] = w_out[0 * 512 + lane * 8 + u];
    w1[u] = w_out[1 * 512 + lane * 8 + u];
    w2[u] = w_out[2 * 512 + lane * 8 + u];
    w3[u] = w_out[3 * 512 + lane * 8 + u];
  }
  float bo0 = b_out[0], bo1 = b_out[1], bo2 = b_out[2], bo3 = b_out[3];
  const f16* src0 = (lane < 32) ? (hsF + lane * 8) : (hsB + (lane - 32) * 8);
  for (int row = gw; row < BB * TT; row += nw) {
    union { uint4 u; f16 h[8]; } hv;
    hv.u = *(const uint4*)(src0 + ((size_t)row << 8));
    float a0 = 0.f, a1 = 0.f, a2 = 0.f, a3 = 0.f;
#pragma unroll
    for (int u2 = 0; u2 < 8; ++u2) {
      float x = (float)hv.h[u2];
      a0 += x * w0[u2]; a1 += x * w1[u2]; a2 += x * w2[u2]; a3 += x * w3[u2];
    }
#pragma unroll
    for (int d = 1; d < 64; d <<= 1) {
      a0 += __shfl_xor(a0, d); a1 += __shfl_xor(a1, d);
      a2 += __shfl_xor(a2, d); a3 += __shfl_xor(a3, d);
    }
    if (lane == 0) {
      floatx4 o = {a0 + bo0, a1 + bo1, a2 + bo2, a3 + bo3};
      *(floatx4*)(feats + (size_t)row * 4) = o;
    }
  }
}

// ---------------- CRF: numerator + forward algorithm, one wave per batch
__global__ void crf_kernel(const int* __restrict__ tags, const int* __restrict__ length,
                           const float* __restrict__ feats,
                           const float* __restrict__ start_trans,
                           const float* __restrict__ end_trans, const float* __restrict__ trans,
                           float* __restrict__ res) {
  int b = blockIdx.x;
  int lane = threadIdx.x;
  int len = length[b];
  float tr0 = lane < 4 ? trans[0 * 4 + lane] : 0.f;
  float tr1 = lane < 4 ? trans[1 * 4 + lane] : 0.f;
  float tr2 = lane < 4 ? trans[2 * 4 + lane] : 0.f;
  float tr3 = lane < 4 ? trans[3 * 4 + lane] : 0.f;
  float treg = lane < 16 ? trans[lane] : 0.f;
  float st = lane < 4 ? start_trans[lane] : 0.f;
  float en = lane < 4 ? end_trans[lane] : 0.f;
  const int* tg = tags + b * TT;
  const float* fb = feats + (size_t)b * TT * 4;

  float e = lane < 4 ? fb[lane] : 0.f;
  int prev = tg[0];
  float alpha = st + e;
  float num = __shfl(st + e, prev);
#pragma unroll 2
  for (int t = 1; t < len; ++t) {
    float et = lane < 4 ? fb[t * 4 + lane] : 0.f;
    int cur = tg[t];
    float a0 = __shfl(alpha, 0), a1 = __shfl(alpha, 1), a2 = __shfl(alpha, 2), a3 = __shfl(alpha, 3);
    float v0 = a0 + tr0, v1 = a1 + tr1, v2 = a2 + tr2, v3 = a3 + tr3;
    float mx = fmaxf(fmaxf(v0, v1), fmaxf(v2, v3));
    float sm = __expf(v0 - mx) + __expf(v1 - mx) + __expf(v2 - mx) + __expf(v3 - mx);
    alpha = mx + __logf(sm) + et;
    num += __shfl(et, cur) + __shfl(treg, prev * 4 + cur);
    prev = cur;
  }
  num += __shfl(en, prev);
  float v = alpha + en;
  float z0 = __shfl(v, 0), z1 = __shfl(v, 1), z2 = __shfl(v, 2), z3 = __shfl(v, 3);
  float mx = fmaxf(fmaxf(z0, z1), fmaxf(z2, z3));
  float logZ = mx + __logf(__expf(z0 - mx) + __expf(z1 - mx) + __expf(z2 - mx) + __expf(z3 - mx));
  if (lane == 0) res[b] = num - logZ;
}

__global__ void loss_kernel(const float* __restrict__ res, float* __restrict__ out) {
  int lane = threadIdx.x;
  float v = res[lane];
#pragma unroll
  for (int d = 1; d < 64; d <<= 1) v += __shfl_xor(v, d);
  if (lane == 0) out[0] = -v * (1.f / 64.f);
}

extern "C" void kernel_launch(void* const* d_in, const int* in_sizes, int n_in,
                              void* d_out, int out_size, void* d_ws, size_t ws_size,
                              hipStream_t stream) {
  (void)in_sizes; (void)n_in; (void)out_size;
  const int* sentence = (const int*)d_in[0];
  const int* tags = (const int*)d_in[1];
  const int* length = (const int*)d_in[3];
  const float* embedding = (const float*)d_in[4];
  const float* w_ih_f = (const float*)d_in[5];
  const float* w_hh_f = (const float*)d_in[6];
  const float* b_f = (const float*)d_in[7];
  const float* w_ih_b = (const float*)d_in[8];
  const float* w_hh_b = (const float*)d_in[9];
  const float* b_b = (const float*)d_in[10];
  const float* w_out = (const float*)d_in[11];
  const float* b_out = (const float*)d_in[12];
  const float* start_trans = (const float*)d_in[13];
  const float* end_trans = (const float*)d_in[14];
  const float* trans = (const float*)d_in[15];

  char* ws = (char*)d_ws;
  size_t off = 0;
  auto take = [&](size_t bytes) -> char* {
    char* p = ws + off;
    off = (off + bytes + 255) & ~(size_t)255;
    return p;
  };
  f16* bmat = (f16*)take((size_t)2048 * 256 * 2);
  uint32_t* whhp = (uint32_t*)take((size_t)2 * 64 * 1024 * 4);
  float* swhh = (float*)take((size_t)2 * 1024 * 4);
  f16* hsF = (f16*)take((size_t)BB * TT * 256 * 2);
  f16* hsB = (f16*)take((size_t)BB * TT * 256 * 2);
  float* feats = (float*)take((size_t)BB * TT * NTAG * 4);
  float* hstate = (float*)take((size_t)2 * BB * 256 * 4);
  float* cstate = (float*)take((size_t)2 * BB * 256 * 4);
  float* res = (float*)take(256);
  size_t fixed = off;

  int L = TT, Lsh = 9;
  while (L > 32 && fixed + (size_t)BB * L * 1024 * 2 * 2 > ws_size) { L >>= 1; Lsh--; }
  f16* xgF = (f16*)take((size_t)BB * L * 1024 * 2);
  f16* xgB = (f16*)take((size_t)BB * L * 1024 * 2);
  int NC = TT / L;

  hipLaunchKernelGGL(pack_kernel, dim3(512), dim3(256), 0, stream,
                     w_ih_f, w_ih_b, w_hh_f, w_hh_b, bmat, whhp, swhh);

  for (int cidx = 0; cidx < NC; ++cidx) {
    int t0f_ = cidx * L;
    int t0b_ = TT - (cidx + 1) * L;
    hipLaunchKernelGGL(gemm_kernel, dim3(2 * BB * L / 128, 8), dim3(256), 0, stream,
                       sentence, embedding, bmat, xgF, xgB, t0f_, t0b_, L, Lsh);
    hipLaunchKernelGGL(rec_kernel, dim3(128), dim3(256), 0, stream,
                       length, xgF, xgB, whhp, swhh, b_f, b_b, hsF, hsB,
                       hstate, cstate, t0f_, t0b_, L, cidx == 0 ? 1 : 0);
  }
  hipLaunchKernelGGL(feats_kernel, dim3(512), dim3(256), 0, stream,
                     hsF, hsB, w_out, b_out, feats);
  hipLaunchKernelGGL(crf_kernel, dim3(BB), dim3(64), 0, stream,
                     tags, length, feats, start_trans, end_trans, trans, res);
  hipLaunchKernelGGL(loss_kernel, dim3(1), dim3(64), 0, stream, res, (float*)d_out);
}

// Round 3
// 1073.650 us; speedup vs baseline: 1.0488x; 1.0488x over previous
//
#include <hip/hip_runtime.h>
#include <stdint.h>

#define BB 64
#define TT 512
#define EE 256
#define NTAG 4

typedef _Float16 f16;
typedef _Float16 half8 __attribute__((ext_vector_type(8)));
typedef _Float16 f16x4 __attribute__((ext_vector_type(4)));
typedef float floatx4 __attribute__((ext_vector_type(4)));

__device__ __forceinline__ int dot4i8(uint32_t a, uint32_t b, int c) {
#if __has_builtin(__builtin_amdgcn_sdot4)
  return __builtin_amdgcn_sdot4((int)a, (int)b, c, false);
#else
  int r;
  asm("v_dot4_i32_i8 %0, %1, %2, %3" : "=v"(r) : "v"(a), "v"(b), "v"(c));
  return r;
#endif
}

__device__ __forceinline__ float sigm(float x) {
  x = fminf(fmaxf(x, -30.f), 30.f);
  return 1.f / (1.f + __expf(-x));
}
__device__ __forceinline__ float tanh_f(float x) {
  x = fminf(fmaxf(x, -15.f), 15.f);
  float e = __expf(-2.f * x);
  return (1.f - e) / (1.f + e);
}

// ---------------- pack: w_ih -> f16 Bmat rows (gate-interleaved output cols);
//                   w_hh -> i8 k4-major + row scales
__global__ void pack_kernel(const float* __restrict__ wihf, const float* __restrict__ wihb,
                            const float* __restrict__ whhf, const float* __restrict__ whhb,
                            f16* __restrict__ bmat, uint32_t* __restrict__ whhp,
                            float* __restrict__ swhh) {
  int wv = (blockIdx.x * 256 + threadIdx.x) >> 6;  // global wave 0..2047
  int lane = threadIdx.x & 63;
  if (wv >= 2048) return;
  int dir = wv >> 10;
  int outr = wv & 1023;  // output col index: dim = outr>>2, gate = outr&3
  int srcg = (outr & 3) * 256 + (outr >> 2);
  const float* wih = dir ? wihb : wihf;
  const float* src = wih + (size_t)srcg * EE + lane * 4;
  f16* bp = bmat + (size_t)wv * EE + lane * 4;
  floatx4 v = *(const floatx4*)src;
  bp[0] = (f16)v[0]; bp[1] = (f16)v[1]; bp[2] = (f16)v[2]; bp[3] = (f16)v[3];
  int g = outr;
  const float* whh = dir ? whhb : whhf;
  floatx4 w = *(const floatx4*)(whh + (size_t)g * EE + lane * 4);
  float am = fmaxf(fmaxf(fabsf(w[0]), fabsf(w[1])), fmaxf(fabsf(w[2]), fabsf(w[3])));
#pragma unroll
  for (int d = 1; d < 64; d <<= 1) am = fmaxf(am, __shfl_xor(am, d));
  float s = am * (1.f / 127.f);
  float inv = am > 0.f ? 127.f / am : 0.f;
  int q0 = (int)rintf(w[0] * inv);
  int q1 = (int)rintf(w[1] * inv);
  int q2 = (int)rintf(w[2] * inv);
  int q3 = (int)rintf(w[3] * inv);
  uint32_t p = (uint32_t)(q0 & 255) | ((uint32_t)(q1 & 255) << 8) |
               ((uint32_t)(q2 & 255) << 16) | ((uint32_t)(q3 & 255) << 24);
  whhp[dir * 65536 + lane * 1024 + g] = p;
  if (lane == 0) swhh[dir * 1024 + g] = s;
}

// ---------------- GEMM: xg = embeds @ w_ih^T  (f16 MFMA, fused embedding gather)
__global__ __launch_bounds__(256) void gemm_kernel(
    const int* __restrict__ sentence, const float* __restrict__ embedding,
    const f16* __restrict__ bmat, f16* __restrict__ xgF, f16* __restrict__ xgB,
    int t0f, int t0b, int L, int Lsh) {
  __shared__ __attribute__((aligned(16))) f16 As[128][72];
  __shared__ __attribute__((aligned(16))) f16 Bs[128][72];
  int rt = blockIdx.x;
  int nt = blockIdx.y;  // 0..7
  int tid = threadIdx.x;
  int lane = tid & 63;
  int wv = tid >> 6;
  int BL = BB * L;
  int rbase = rt * 128;
  int half = (rbase >= BL) ? 1 : 0;
  int rloc0 = rbase - half * BL;
  int t0 = half ? t0b : t0f;

  floatx4 acc[4][4];
#pragma unroll
  for (int i = 0; i < 4; ++i)
#pragma unroll
    for (int j = 0; j < 4; ++j) acc[i][j] = (floatx4){0.f, 0.f, 0.f, 0.f};

  int ar = tid >> 1;
  int part = tid & 1;
  int rl = rloc0 + ar;
  int b_ = rl >> Lsh;
  int dt = rl & (L - 1);
  int t_ = t0 + dt;
  int sidx = sentence[b_ * TT + t_];
  const float* arow = embedding + (size_t)sidx * EE + part * 32;
  const f16* brow = bmat + ((size_t)(half * 1024 + nt * 128 + ar)) * EE + part * 32;
  int wm = (wv >> 1) * 64, wn = (wv & 1) * 64;

  for (int kk = 0; kk < 4; ++kk) {
    int k0 = kk * 64;
#pragma unroll
    for (int i = 0; i < 4; ++i) {
      floatx4 a0 = *(const floatx4*)(arow + k0 + i * 8);
      floatx4 a1 = *(const floatx4*)(arow + k0 + i * 8 + 4);
      union { f16 h[8]; uint4 u; } cv;
      cv.h[0] = (f16)a0[0]; cv.h[1] = (f16)a0[1]; cv.h[2] = (f16)a0[2]; cv.h[3] = (f16)a0[3];
      cv.h[4] = (f16)a1[0]; cv.h[5] = (f16)a1[1]; cv.h[6] = (f16)a1[2]; cv.h[7] = (f16)a1[3];
      *(uint4*)(&As[ar][part * 32 + i * 8]) = cv.u;
    }
#pragma unroll
    for (int i = 0; i < 4; ++i) {
      uint4 bv = *(const uint4*)(brow + k0 + i * 8);
      *(uint4*)(&Bs[ar][part * 32 + i * 8]) = bv;
    }
    __syncthreads();
#pragma unroll
    for (int kf = 0; kf < 2; ++kf) {
      int ko = kf * 32 + (lane >> 4) * 8;
      half8 af[4], bf[4];
#pragma unroll
      for (int mi = 0; mi < 4; ++mi)
        af[mi] = *(const half8*)(&As[wm + mi * 16 + (lane & 15)][ko]);
#pragma unroll
      for (int ni = 0; ni < 4; ++ni)
        bf[ni] = *(const half8*)(&Bs[wn + ni * 16 + (lane & 15)][ko]);
#pragma unroll
      for (int mi = 0; mi < 4; ++mi)
#pragma unroll
        for (int ni = 0; ni < 4; ++ni)
          acc[mi][ni] = __builtin_amdgcn_mfma_f32_16x16x32_f16(af[mi], bf[ni], acc[mi][ni], 0, 0, 0);
    }
    __syncthreads();
  }
  f16* out = half ? xgB : xgF;
#pragma unroll
  for (int mi = 0; mi < 4; ++mi) {
#pragma unroll
    for (int ni = 0; ni < 4; ++ni) {
      int rowl = wm + mi * 16 + (lane >> 4) * 4;
      int coll = nt * 128 + wn + ni * 16 + (lane & 15);
#pragma unroll
      for (int r = 0; r < 4; ++r) {
        out[(size_t)(rloc0 + rowl + r) * 1024 + coll] = (f16)acc[mi][ni][r];
      }
    }
  }
}

// ---------------- recurrence: 128 WGs (b,dir), 256 threads, 1 h-dim/thread,
// weights as NAMED SCALARS (rule #20: no arrays -> guaranteed VGPR-resident)
#define R16(M) M(0) M(1) M(2) M(3) M(4) M(5) M(6) M(7) M(8) M(9) M(10) M(11) M(12) M(13) M(14) M(15)

#define LDW(k) \
  uint32_t wi0_##k = wp[(4*(k)+0)*1024 + j];       uint32_t wi1_##k = wp[(4*(k)+1)*1024 + j]; \
  uint32_t wi2_##k = wp[(4*(k)+2)*1024 + j];       uint32_t wi3_##k = wp[(4*(k)+3)*1024 + j]; \
  uint32_t wf0_##k = wp[(4*(k)+0)*1024 + 256 + j]; uint32_t wf1_##k = wp[(4*(k)+1)*1024 + 256 + j]; \
  uint32_t wf2_##k = wp[(4*(k)+2)*1024 + 256 + j]; uint32_t wf3_##k = wp[(4*(k)+3)*1024 + 256 + j]; \
  uint32_t wg0_##k = wp[(4*(k)+0)*1024 + 512 + j]; uint32_t wg1_##k = wp[(4*(k)+1)*1024 + 512 + j]; \
  uint32_t wg2_##k = wp[(4*(k)+2)*1024 + 512 + j]; uint32_t wg3_##k = wp[(4*(k)+3)*1024 + 512 + j]; \
  uint32_t wo0_##k = wp[(4*(k)+0)*1024 + 768 + j]; uint32_t wo1_##k = wp[(4*(k)+1)*1024 + 768 + j]; \
  uint32_t wo2_##k = wp[(4*(k)+2)*1024 + 768 + j]; uint32_t wo3_##k = wp[(4*(k)+3)*1024 + 768 + j];

#define DOT(k) { uint4 hv = rb[k]; \
  Ai0 = dot4i8(wi0_##k, hv.x, Ai0); Ai1 = dot4i8(wi1_##k, hv.y, Ai1); \
  Ai0 = dot4i8(wi2_##k, hv.z, Ai0); Ai1 = dot4i8(wi3_##k, hv.w, Ai1); \
  Af0 = dot4i8(wf0_##k, hv.x, Af0); Af1 = dot4i8(wf1_##k, hv.y, Af1); \
  Af0 = dot4i8(wf2_##k, hv.z, Af0); Af1 = dot4i8(wf3_##k, hv.w, Af1); \
  Ag0 = dot4i8(wg0_##k, hv.x, Ag0); Ag1 = dot4i8(wg1_##k, hv.y, Ag1); \
  Ag0 = dot4i8(wg2_##k, hv.z, Ag0); Ag1 = dot4i8(wg3_##k, hv.w, Ag1); \
  Ao0 = dot4i8(wo0_##k, hv.x, Ao0); Ao1 = dot4i8(wo1_##k, hv.y, Ao1); \
  Ao0 = dot4i8(wo2_##k, hv.z, Ao0); Ao1 = dot4i8(wo3_##k, hv.w, Ao1); }

__global__ __launch_bounds__(256, 1) void rec_kernel(
    const int* __restrict__ length, const f16* __restrict__ xgF, const f16* __restrict__ xgB,
    const uint32_t* __restrict__ whhp, const float* __restrict__ swhh,
    const float* __restrict__ b_f, const float* __restrict__ b_b,
    f16* __restrict__ hsF, f16* __restrict__ hsB,
    float* __restrict__ hstate, float* __restrict__ cstate,
    int t0f, int t0b, int L, int first) {
  __shared__ __attribute__((aligned(16))) uint32_t hq4[2][64];
  int wid = blockIdx.x;
  int b = wid >> 1, dir = wid & 1;
  int j = threadIdx.x;  // h dim 0..255
  int len = length[b];

  const uint32_t* wp = whhp + dir * 65536;
  R16(LDW)

  const float* sb = swhh + dir * 1024;
  float sw0 = sb[j] * (1.f / 127.f), sw1 = sb[256 + j] * (1.f / 127.f);
  float sw2 = sb[512 + j] * (1.f / 127.f), sw3 = sb[768 + j] * (1.f / 127.f);
  const float* bias = dir ? b_b : b_f;
  float bi0 = bias[j], bi1 = bias[256 + j], bi2 = bias[512 + j], bi3 = bias[768 + j];

  float h = 0.f, c = 0.f;
  if (!first) {
    h = hstate[(dir * BB + b) * 256 + j];
    c = cstate[(dir * BB + b) * 256 + j];
  }
  const f16* xg = dir ? xgB : xgF;
  f16* hs = dir ? hsB : hsF;

  int qi = (int)rintf(h * 127.f);
  qi = max(-127, min(127, qi));
  ((uint8_t*)&hq4[0][0])[j] = (uint8_t)qi;
  __syncthreads();

  int tlo = dir ? t0b : t0f;
  int thi = min(tlo + L, len);
  int nsteps = thi - tlo;
  int p = 0;
  // software-pipelined xg load
  int r0 = b * L + (dir ? (thi - 1 - tlo) : 0);
  int sgn = dir ? -1 : 1;
  f16x4 xv_cur = (nsteps > 0) ? *(const f16x4*)(xg + (((size_t)r0) << 10) + j * 4)
                              : (f16x4){0, 0, 0, 0};
  for (int ii = 0; ii < nsteps; ++ii) {
    f16x4 xv_nxt = xv_cur;
    if (ii + 1 < nsteps)
      xv_nxt = *(const f16x4*)(xg + (((size_t)(r0 + sgn * (ii + 1))) << 10) + j * 4);
    const uint4* rb = (const uint4*)(&hq4[p][0]);
    int Ai0 = 0, Ai1 = 0, Af0 = 0, Af1 = 0, Ag0 = 0, Ag1 = 0, Ao0 = 0, Ao1 = 0;
    R16(DOT)
    float pi = (float)xv_cur[0] + bi0 + sw0 * (float)(Ai0 + Ai1);
    float pf = (float)xv_cur[1] + bi1 + sw1 * (float)(Af0 + Af1);
    float pg = (float)xv_cur[2] + bi2 + sw2 * (float)(Ag0 + Ag1);
    float po = (float)xv_cur[3] + bi3 + sw3 * (float)(Ao0 + Ao1);
    float iv = sigm(pi), fv = sigm(pf), gv = tanh_f(pg), ov = sigm(po);
    c = fv * c + iv * gv;
    h = ov * tanh_f(c);
    int t = dir ? (thi - 1 - ii) : (tlo + ii);
    hs[(((size_t)(b * TT + t)) << 8) + j] = (f16)h;  // fire-and-forget
    int q = (int)rintf(h * 127.f);
    q = max(-127, min(127, q));
    ((uint8_t*)&hq4[p ^ 1][0])[j] = (uint8_t)q;
    __syncthreads();
    p ^= 1;
    xv_cur = xv_nxt;
  }
  hstate[(dir * BB + b) * 256 + j] = h;
  cstate[(dir * BB + b) * 256 + j] = c;
}

// ---------------- feats: [hf|hb] @ w_out^T + b_out, one wave per row
__global__ __launch_bounds__(256) void feats_kernel(
    const f16* __restrict__ hsF, const f16* __restrict__ hsB,
    const float* __restrict__ w_out, const float* __restrict__ b_out,
    float* __restrict__ feats) {
  int gw = (blockIdx.x * 256 + threadIdx.x) >> 6;
  int lane = threadIdx.x & 63;
  int nw = (gridDim.x * 256) >> 6;
  float w0[8], w1[8], w2[8], w3[8];
#pragma unroll
  for (int u = 0; u < 8; ++u) {
    w0[u] = w_out[0 * 512 + lane * 8 + u];
    w1[u] = w_out[1 * 512 + lane * 8 + u];
    w2[u] = w_out[2 * 512 + lane * 8 + u];
    w3[u] = w_out[3 * 512 + lane * 8 + u];
  }
  float bo0 = b_out[0], bo1 = b_out[1], bo2 = b_out[2], bo3 = b_out[3];
  const f16* src0 = (lane < 32) ? (hsF + lane * 8) : (hsB + (lane - 32) * 8);
  for (int row = gw; row < BB * TT; row += nw) {
    union { uint4 u; f16 h[8]; } hv;
    hv.u = *(const uint4*)(src0 + ((size_t)row << 8));
    float a0 = 0.f, a1 = 0.f, a2 = 0.f, a3 = 0.f;
#pragma unroll
    for (int u2 = 0; u2 < 8; ++u2) {
      float x = (float)hv.h[u2];
      a0 += x * w0[u2]; a1 += x * w1[u2]; a2 += x * w2[u2]; a3 += x * w3[u2];
    }
#pragma unroll
    for (int d = 1; d < 64; d <<= 1) {
      a0 += __shfl_xor(a0, d); a1 += __shfl_xor(a1, d);
      a2 += __shfl_xor(a2, d); a3 += __shfl_xor(a3, d);
    }
    if (lane == 0) {
      floatx4 o = {a0 + bo0, a1 + bo1, a2 + bo2, a3 + bo3};
      *(floatx4*)(feats + (size_t)row * 4) = o;
    }
  }
}

// ---------------- CRF: numerator + forward algorithm, one wave per batch
__global__ void crf_kernel(const int* __restrict__ tags, const int* __restrict__ length,
                           const float* __restrict__ feats,
                           const float* __restrict__ start_trans,
                           const float* __restrict__ end_trans, const float* __restrict__ trans,
                           float* __restrict__ res) {
  int b = blockIdx.x;
  int lane = threadIdx.x;
  int len = length[b];
  float tr0 = lane < 4 ? trans[0 * 4 + lane] : 0.f;
  float tr1 = lane < 4 ? trans[1 * 4 + lane] : 0.f;
  float tr2 = lane < 4 ? trans[2 * 4 + lane] : 0.f;
  float tr3 = lane < 4 ? trans[3 * 4 + lane] : 0.f;
  float treg = lane < 16 ? trans[lane] : 0.f;
  float st = lane < 4 ? start_trans[lane] : 0.f;
  float en = lane < 4 ? end_trans[lane] : 0.f;
  const int* tg = tags + b * TT;
  const float* fb = feats + (size_t)b * TT * 4;

  float e = lane < 4 ? fb[lane] : 0.f;
  int prev = tg[0];
  float alpha = st + e;
  float num = __shfl(st + e, prev);
#pragma unroll 2
  for (int t = 1; t < len; ++t) {
    float et = lane < 4 ? fb[t * 4 + lane] : 0.f;
    int cur = tg[t];
    float a0 = __shfl(alpha, 0), a1 = __shfl(alpha, 1), a2 = __shfl(alpha, 2), a3 = __shfl(alpha, 3);
    float v0 = a0 + tr0, v1 = a1 + tr1, v2 = a2 + tr2, v3 = a3 + tr3;
    float mx = fmaxf(fmaxf(v0, v1), fmaxf(v2, v3));
    float sm = __expf(v0 - mx) + __expf(v1 - mx) + __expf(v2 - mx) + __expf(v3 - mx);
    alpha = mx + __logf(sm) + et;
    num += __shfl(et, cur) + __shfl(treg, prev * 4 + cur);
    prev = cur;
  }
  num += __shfl(en, prev);
  float v = alpha + en;
  float z0 = __shfl(v, 0), z1 = __shfl(v, 1), z2 = __shfl(v, 2), z3 = __shfl(v, 3);
  float mx = fmaxf(fmaxf(z0, z1), fmaxf(z2, z3));
  float logZ = mx + __logf(__expf(z0 - mx) + __expf(z1 - mx) + __expf(z2 - mx) + __expf(z3 - mx));
  if (lane == 0) res[b] = num - logZ;
}

__global__ void loss_kernel(const float* __restrict__ res, float* __restrict__ out) {
  int lane = threadIdx.x;
  float v = res[lane];
#pragma unroll
  for (int d = 1; d < 64; d <<= 1) v += __shfl_xor(v, d);
  if (lane == 0) out[0] = -v * (1.f / 64.f);
}

extern "C" void kernel_launch(void* const* d_in, const int* in_sizes, int n_in,
                              void* d_out, int out_size, void* d_ws, size_t ws_size,
                              hipStream_t stream) {
  (void)in_sizes; (void)n_in; (void)out_size;
  const int* sentence = (const int*)d_in[0];
  const int* tags = (const int*)d_in[1];
  const int* length = (const int*)d_in[3];
  const float* embedding = (const float*)d_in[4];
  const float* w_ih_f = (const float*)d_in[5];
  const float* w_hh_f = (const float*)d_in[6];
  const float* b_f = (const float*)d_in[7];
  const float* w_ih_b = (const float*)d_in[8];
  const float* w_hh_b = (const float*)d_in[9];
  const float* b_b = (const float*)d_in[10];
  const float* w_out = (const float*)d_in[11];
  const float* b_out = (const float*)d_in[12];
  const float* start_trans = (const float*)d_in[13];
  const float* end_trans = (const float*)d_in[14];
  const float* trans = (const float*)d_in[15];

  char* ws = (char*)d_ws;
  size_t off = 0;
  auto take = [&](size_t bytes) -> char* {
    char* p = ws + off;
    off = (off + bytes + 255) & ~(size_t)255;
    return p;
  };
  f16* bmat = (f16*)take((size_t)2048 * 256 * 2);
  uint32_t* whhp = (uint32_t*)take((size_t)2 * 64 * 1024 * 4);
  float* swhh = (float*)take((size_t)2 * 1024 * 4);
  f16* hsF = (f16*)take((size_t)BB * TT * 256 * 2);
  f16* hsB = (f16*)take((size_t)BB * TT * 256 * 2);
  float* feats = (float*)take((size_t)BB * TT * NTAG * 4);
  float* hstate = (float*)take((size_t)2 * BB * 256 * 4);
  float* cstate = (float*)take((size_t)2 * BB * 256 * 4);
  float* res = (float*)take(256);
  size_t fixed = off;

  int L = TT, Lsh = 9;
  while (L > 32 && fixed + (size_t)BB * L * 1024 * 2 * 2 > ws_size) { L >>= 1; Lsh--; }
  f16* xgF = (f16*)take((size_t)BB * L * 1024 * 2);
  f16* xgB = (f16*)take((size_t)BB * L * 1024 * 2);
  int NC = TT / L;

  hipLaunchKernelGGL(pack_kernel, dim3(512), dim3(256), 0, stream,
                     w_ih_f, w_ih_b, w_hh_f, w_hh_b, bmat, whhp, swhh);

  for (int cidx = 0; cidx < NC; ++cidx) {
    int t0f_ = cidx * L;
    int t0b_ = TT - (cidx + 1) * L;
    hipLaunchKernelGGL(gemm_kernel, dim3(2 * BB * L / 128, 8), dim3(256), 0, stream,
                       sentence, embedding, bmat, xgF, xgB, t0f_, t0b_, L, Lsh);
    hipLaunchKernelGGL(rec_kernel, dim3(128), dim3(256), 0, stream,
                       length, xgF, xgB, whhp, swhh, b_f, b_b, hsF, hsB,
                       hstate, cstate, t0f_, t0b_, L, cidx == 0 ? 1 : 0);
  }
  hipLaunchKernelGGL(feats_kernel, dim3(512), dim3(256), 0, stream,
                     hsF, hsB, w_out, b_out, feats);
  hipLaunchKernelGGL(crf_kernel, dim3(BB), dim3(64), 0, stream,
                     tags, length, feats, start_trans, end_trans, trans, res);
  hipLaunchKernelGGL(loss_kernel, dim3(1), dim3(64), 0, stream, res, (float*)d_out);
}